// Round 1
// baseline (4557.451 us; speedup 1.0000x reference)
//
#include <hip/hip_runtime.h>

typedef unsigned short u16;
typedef __bf16 bf16x8 __attribute__((ext_vector_type(8)));
typedef float f32x4 __attribute__((ext_vector_type(4)));
typedef unsigned short u16x4 __attribute__((ext_vector_type(4)));
typedef unsigned short u16x8 __attribute__((ext_vector_type(8)));

__device__ __forceinline__ u16 f2bf(float f) {
    union { float f; unsigned u; } v; v.f = f;
    unsigned r = v.u + 0x7FFFu + ((v.u >> 16) & 1u);   // RTNE
    return (u16)(r >> 16);
}
__device__ __forceinline__ float bf2f(u16 h) {
    union { unsigned u; float f; } v; v.u = ((unsigned)h) << 16;
    return v.f;
}

// async global->LDS, 16B per lane; LDS dest is wave-uniform base + lane*16
__device__ __forceinline__ void gl_lds16(const void* gp, void* lp) {
    __builtin_amdgcn_global_load_lds(
        reinterpret_cast<__attribute__((address_space(1))) unsigned int*>(
            reinterpret_cast<size_t>(gp)),
        reinterpret_cast<__attribute__((address_space(3))) unsigned int*>(
            reinterpret_cast<size_t>(lp)),
        16, 0, 0);
}

// Dequant AWQ int4 (stored as int32 in [0,16)) -> bf16, transposed to W^T[n][k].
// q: [K,N] int32 row-major; s,z: [K/128, N] fp32; wt: [N,K] bf16.
// grid: (N/256, K/128), block 256. Each thread owns one n, a 128-wide k chunk.
__global__ __launch_bounds__(256) void dequant_k(
    const int* __restrict__ q, const float* __restrict__ s,
    const float* __restrict__ z, u16* __restrict__ wt, int K, int N)
{
    const int n  = blockIdx.x * 256 + threadIdx.x;
    const int k0 = blockIdx.y * 128;
    const int g  = k0 >> 7;                      // group = 128, k-chunk aligned
    const float sv = s[(size_t)g * N + n];
    const float zv = z[(size_t)g * N + n];
    for (int kc = 0; kc < 128; kc += 8) {
        u16x8 p;
#pragma unroll
        for (int j = 0; j < 8; ++j) {
            int qv = q[(size_t)(k0 + kc + j) * N + n];   // coalesced across lanes
            p[j] = f2bf((float)(qv - 8) * sv + zv);
        }
        *(u16x8*)&wt[(size_t)n * K + k0 + kc] = p;       // 16B per-lane store
    }
}

// m97-structure GEMM: C[m,n] = sum_k A[m,k] * BT[n,k]
// block 256 (4 waves), tile 128x128, BK=32, mfma_f32_16x16x32_bf16, 4x4 tiles/wave.
// AMODE: 0 = A fp32 (convert to bf16 in staging), 1 = A bf16 (global_load_lds).
// EPI:   0 = store bf16 to ghp; 1 = ghp = silu(ghp)*acc (bf16); 2 = store fp32 out.
template <int AMODE, int EPI>
__global__ __launch_bounds__(256, 2) void gemm_k(
    const void* __restrict__ Ap, const u16* __restrict__ Bt,
    u16* __restrict__ ghp, float* __restrict__ outp, int M, int N, int K)
{
    __shared__ __align__(16) u16 A_s[128 * 32];
    __shared__ __align__(16) u16 B_s[128 * 32];

    const int t    = threadIdx.x;
    const int lane = t & 63;
    const int w    = t >> 6;
    const int wy   = w >> 1, wx = w & 1;
    const int m0   = blockIdx.x * 128;
    const int n0   = blockIdx.y * 128;

    const int lr = lane & 15;
    const int kq = (lane >> 4) << 3;

    f32x4 acc[4][4] = {};

    for (int kt = 0; kt < K; kt += 32) {
        // ---- stage B (bf16 W^T rows, k-contiguous) via global_load_lds ----
#pragma unroll
        for (int i = 0; i < 2; ++i) {
            int f   = (w * 2 + i) * 64 + lane;    // 16B chunk id, 0..511
            int row = f >> 2;                     // 32 bf16 per row = 4 chunks
            int ko  = (f & 3) << 3;
            gl_lds16(Bt + (size_t)(n0 + row) * K + kt + ko,
                     (char*)B_s + ((w * 2 + i) << 10));
        }
        // ---- stage A ----
        if (AMODE == 1) {
            const u16* ab = (const u16*)Ap;
#pragma unroll
            for (int i = 0; i < 2; ++i) {
                int f   = (w * 2 + i) * 64 + lane;
                int row = f >> 2;
                int ko  = (f & 3) << 3;
                gl_lds16(ab + (size_t)(m0 + row) * K + kt + ko,
                         (char*)A_s + ((w * 2 + i) << 10));
            }
        } else {
            const float* xa = (const float*)Ap;
#pragma unroll
            for (int i = 0; i < 4; ++i) {
                int c   = t + (i << 8);           // float4 chunk id, 0..1023
                int row = c >> 3;                 // 32 floats per row = 8 chunks
                int ko  = (c & 7) << 2;
                float4 v = *(const float4*)(xa + (size_t)(m0 + row) * K + kt + ko);
                u16x4 p;
                p.x = f2bf(v.x); p.y = f2bf(v.y); p.z = f2bf(v.z); p.w = f2bf(v.w);
                *(u16x4*)&A_s[row * 32 + ko] = p;
            }
        }
        __syncthreads();

        bf16x8 af[4], bv[4];
#pragma unroll
        for (int i = 0; i < 4; ++i)
            af[i] = *(const bf16x8*)&A_s[(wy * 64 + i * 16 + lr) * 32 + kq];
#pragma unroll
        for (int j = 0; j < 4; ++j)
            bv[j] = *(const bf16x8*)&B_s[(wx * 64 + j * 16 + lr) * 32 + kq];
#pragma unroll
        for (int i = 0; i < 4; ++i)
#pragma unroll
            for (int j = 0; j < 4; ++j)
                acc[i][j] = __builtin_amdgcn_mfma_f32_16x16x32_bf16(
                    af[i], bv[j], acc[i][j], 0, 0, 0);
        __syncthreads();
    }

    // ---- epilogue: C/D layout col=lane&15, row=(lane>>4)*4+reg ----
    const int r0 = (lane >> 4) << 2;
    const int cc = lane & 15;
#pragma unroll
    for (int i = 0; i < 4; ++i) {
#pragma unroll
        for (int j = 0; j < 4; ++j) {
#pragma unroll
            for (int r = 0; r < 4; ++r) {
                size_t row = (size_t)(m0 + wy * 64 + i * 16 + r0 + r);
                size_t col = (size_t)(n0 + wx * 64 + j * 16 + cc);
                size_t idx = row * (size_t)N + col;
                float v = acc[i][j][r];
                if (EPI == 0) {
                    ghp[idx] = f2bf(v);
                } else if (EPI == 1) {
                    float g  = bf2f(ghp[idx]);
                    float sg = g / (1.0f + __expf(-g));
                    ghp[idx] = f2bf(sg * v);
                } else {
                    outp[idx] = v;
                }
            }
        }
    }
}

extern "C" void kernel_launch(void* const* d_in, const int* in_sizes, int n_in,
                              void* d_out, int out_size, void* d_ws, size_t ws_size,
                              hipStream_t stream) {
    const float* x  = (const float*)d_in[0];
    const int*   gq = (const int*)  d_in[1];
    const float* gs = (const float*)d_in[2];
    const float* gz = (const float*)d_in[3];
    const int*   uq = (const int*)  d_in[4];
    const float* us = (const float*)d_in[5];
    const float* uz = (const float*)d_in[6];
    const int*   dq = (const int*)  d_in[7];
    const float* dsc= (const float*)d_in[8];
    const float* dz = (const float*)d_in[9];
    float* out = (float*)d_out;

    const int D = 4096, I = 11008, M = 8192;

    // ws layout: W^T scratch (90.2 MB, reused 3x) | gate/h bf16 buffer (180.4 MB)
    u16* Wt = (u16*)d_ws;
    u16* gh = (u16*)((char*)d_ws + (size_t)I * D * 2);

    dim3 blk(256);

    // gate: Wg^T then gate = x @ Wg -> gh (bf16)
    dequant_k<<<dim3(I / 256, D / 128), blk, 0, stream>>>(gq, gs, gz, Wt, D, I);
    gemm_k<0, 0><<<dim3(M / 128, I / 128), blk, 0, stream>>>(x, Wt, gh, nullptr, M, I, D);

    // up: Wu^T then h = silu(gate) * (x @ Wu), in place in gh
    dequant_k<<<dim3(I / 256, D / 128), blk, 0, stream>>>(uq, us, uz, Wt, D, I);
    gemm_k<0, 1><<<dim3(M / 128, I / 128), blk, 0, stream>>>(x, Wt, gh, nullptr, M, I, D);

    // down: Wd^T then out = h @ Wd (fp32 out)
    dequant_k<<<dim3(D / 256, I / 128), blk, 0, stream>>>(dq, dsc, dz, Wt, I, D);
    gemm_k<1, 2><<<dim3(M / 128, D / 128), blk, 0, stream>>>(gh, Wt, nullptr, out, M, D, I);
}

// Round 2
// 3729.277 us; speedup vs baseline: 1.2221x; 1.2221x over previous
//
#include <hip/hip_runtime.h>

typedef unsigned short u16;
typedef __bf16 bf16x8 __attribute__((ext_vector_type(8)));
typedef float f32x4 __attribute__((ext_vector_type(4)));
typedef unsigned short u16x4 __attribute__((ext_vector_type(4)));
typedef unsigned short u16x8 __attribute__((ext_vector_type(8)));

__device__ __forceinline__ u16 f2bf(float f) {
    union { float f; unsigned u; } v; v.f = f;
    unsigned r = v.u + 0x7FFFu + ((v.u >> 16) & 1u);   // RTNE
    return (u16)(r >> 16);
}
__device__ __forceinline__ float bf2f(u16 h) {
    union { unsigned u; float f; } v; v.u = ((unsigned)h) << 16;
    return v.f;
}

// async global->LDS, 16B per lane; LDS dest is wave-uniform base + lane*16
__device__ __forceinline__ void gl_lds16(const void* gp, void* lp) {
    __builtin_amdgcn_global_load_lds(
        reinterpret_cast<__attribute__((address_space(1))) unsigned int*>(
            reinterpret_cast<size_t>(gp)),
        reinterpret_cast<__attribute__((address_space(3))) unsigned int*>(
            reinterpret_cast<size_t>(lp)),
        16, 0, 0);
}

// GROUP_M=8 swizzle: 8 m-blocks x all n per group -> A panel (8 MB) stays L2-hot
__device__ __forceinline__ void swz(int bid, int nb, int& mb, int& nbk) {
    int gs  = nb << 3;
    int grp = bid / gs;
    int rem = bid - grp * gs;
    mb  = (grp << 3) + (rem & 7);
    nbk = rem >> 3;
}

// ---- x fp32 -> bf16, 8 elems/thread, exact grid ----
__global__ __launch_bounds__(256) void xcvt(const float* __restrict__ x,
                                            u16* __restrict__ xb) {
    size_t i = ((size_t)blockIdx.x * 256 + threadIdx.x) * 8;
    float4 a = *(const float4*)(x + i);
    float4 b = *(const float4*)(x + i + 4);
    u16x8 p;
    p[0] = f2bf(a.x); p[1] = f2bf(a.y); p[2] = f2bf(a.z); p[3] = f2bf(a.w);
    p[4] = f2bf(b.x); p[5] = f2bf(b.y); p[6] = f2bf(b.z); p[7] = f2bf(b.w);
    *(u16x8*)(xb + i) = p;
}

// ---- transpose-dequant via LDS: q[K,N] int32 -> wt[N,K] bf16 ----
// tile 128k x 64n, block 256. Phase1: coalesced int4 reads, dequant, LDS[n][k]
// (row stride 132 u16: 4-way max bank alias on writes, 8B-aligned rows).
// Phase2: coalesced 16B global writes along k.
__global__ __launch_bounds__(256) void dequant_t(
    const int* __restrict__ q, const float* __restrict__ s,
    const float* __restrict__ z, u16* __restrict__ wt, int K, int N)
{
    __shared__ u16 ls[64 * 132];
    const int n0 = blockIdx.x * 64, k0 = blockIdx.y * 128;
    const int g  = k0 >> 7;
    const int t  = threadIdx.x;
    const int n4 = (t & 15) * 4;
    const int kb = t >> 4;
    float sv[4], zv[4];
#pragma unroll
    for (int j = 0; j < 4; ++j) {
        sv[j] = s[(size_t)g * N + n0 + n4 + j];
        zv[j] = z[(size_t)g * N + n0 + n4 + j];
    }
#pragma unroll
    for (int p = 0; p < 8; ++p) {
        int kk = kb + p * 16;
        int4 qv = *(const int4*)(q + (size_t)(k0 + kk) * N + n0 + n4);
        ls[(n4 + 0) * 132 + kk] = f2bf((float)(qv.x - 8) * sv[0] + zv[0]);
        ls[(n4 + 1) * 132 + kk] = f2bf((float)(qv.y - 8) * sv[1] + zv[1]);
        ls[(n4 + 2) * 132 + kk] = f2bf((float)(qv.z - 8) * sv[2] + zv[2]);
        ls[(n4 + 3) * 132 + kk] = f2bf((float)(qv.w - 8) * sv[3] + zv[3]);
    }
    __syncthreads();
    const int r = t >> 2, c = t & 3;
    const u16* src = &ls[r * 132 + c * 32];
    u16* dst = &wt[(size_t)(n0 + r) * K + k0 + c * 32];
#pragma unroll
    for (int i = 0; i < 4; ++i) {
        u16x4 a = *(const u16x4*)(src + i * 8);       // 8B-aligned LDS reads
        u16x4 b = *(const u16x4*)(src + i * 8 + 4);
        u16x8 v;
        v[0] = a[0]; v[1] = a[1]; v[2] = a[2]; v[3] = a[3];
        v[4] = b[0]; v[5] = b[1]; v[6] = b[2]; v[7] = b[3];
        *(u16x8*)(dst + i * 8) = v;                   // 16B coalesced store
    }
}

// ---- fused gate+up GEMM: shared A tile, two B tiles, silu(g)*u epilogue ----
// block 256 (4 waves), tile 128x128, BK=32, mfma_f32_16x16x32_bf16.
__global__ __launch_bounds__(256, 2) void gu_gemm(
    const u16* __restrict__ xb, const u16* __restrict__ Bg,
    const u16* __restrict__ Bu, u16* __restrict__ gh, int M, int N, int K)
{
    __shared__ __align__(16) u16 A_s[128 * 32];
    __shared__ __align__(16) u16 G_s[128 * 32];
    __shared__ __align__(16) u16 U_s[128 * 32];

    const int nb = N >> 7;
    int mb, nbk; swz(blockIdx.x, nb, mb, nbk);
    const int m0 = mb << 7, n0 = nbk << 7;
    const int t = threadIdx.x, lane = t & 63, w = t >> 6;
    const int wy = w >> 1, wx = w & 1;
    const int lr = lane & 15, kq = (lane >> 4) << 3;

    f32x4 ag[4][4] = {}, au[4][4] = {};

    for (int kt = 0; kt < K; kt += 32) {
#pragma unroll
        for (int i = 0; i < 2; ++i) {
            int f   = (w * 2 + i) * 64 + lane;
            int row = f >> 2;
            int ko  = (f & 3) << 3;
            size_t bo = (size_t)(n0 + row) * K + kt + ko;
            gl_lds16(xb + (size_t)(m0 + row) * K + kt + ko,
                     (char*)A_s + ((w * 2 + i) << 10));
            gl_lds16(Bg + bo, (char*)G_s + ((w * 2 + i) << 10));
            gl_lds16(Bu + bo, (char*)U_s + ((w * 2 + i) << 10));
        }
        __syncthreads();

        bf16x8 af[4], bg[4], bu[4];
#pragma unroll
        for (int i = 0; i < 4; ++i)
            af[i] = *(const bf16x8*)&A_s[(wy * 64 + i * 16 + lr) * 32 + kq];
#pragma unroll
        for (int j = 0; j < 4; ++j) {
            bg[j] = *(const bf16x8*)&G_s[(wx * 64 + j * 16 + lr) * 32 + kq];
            bu[j] = *(const bf16x8*)&U_s[(wx * 64 + j * 16 + lr) * 32 + kq];
        }
#pragma unroll
        for (int i = 0; i < 4; ++i)
#pragma unroll
            for (int j = 0; j < 4; ++j) {
                ag[i][j] = __builtin_amdgcn_mfma_f32_16x16x32_bf16(
                    af[i], bg[j], ag[i][j], 0, 0, 0);
                au[i][j] = __builtin_amdgcn_mfma_f32_16x16x32_bf16(
                    af[i], bu[j], au[i][j], 0, 0, 0);
            }
        __syncthreads();
    }

    const int r0 = (lane >> 4) << 2, cc = lane & 15;
#pragma unroll
    for (int i = 0; i < 4; ++i)
#pragma unroll
        for (int j = 0; j < 4; ++j)
#pragma unroll
            for (int r = 0; r < 4; ++r) {
                size_t row = (size_t)(m0 + wy * 64 + i * 16 + r0 + r);
                size_t col = (size_t)(n0 + wx * 64 + j * 16 + cc);
                float g = ag[i][j][r], u = au[i][j][r];
                float h = g / (1.0f + __expf(-g)) * u;
                gh[row * (size_t)N + col] = f2bf(h);
            }
}

// ---- single GEMM (fallback path + down GEMM): C[m,n] = sum_k A[m,k]*BT[n,k]
// AMODE: 0 = A fp32 (convert in staging), 1 = A bf16 (global_load_lds).
// EPI:   0 = store bf16; 1 = ghp = silu(ghp)*acc; 2 = store fp32 out.
template <int AMODE, int EPI>
__global__ __launch_bounds__(256, 2) void gemm_k(
    const void* __restrict__ Ap, const u16* __restrict__ Bt,
    u16* __restrict__ ghp, float* __restrict__ outp, int M, int N, int K)
{
    __shared__ __align__(16) u16 A_s[128 * 32];
    __shared__ __align__(16) u16 B_s[128 * 32];

    const int nb = N >> 7;
    int mb, nbk; swz(blockIdx.x, nb, mb, nbk);
    const int m0 = mb << 7, n0 = nbk << 7;
    const int t = threadIdx.x, lane = t & 63, w = t >> 6;
    const int wy = w >> 1, wx = w & 1;
    const int lr = lane & 15, kq = (lane >> 4) << 3;

    f32x4 acc[4][4] = {};

    for (int kt = 0; kt < K; kt += 32) {
#pragma unroll
        for (int i = 0; i < 2; ++i) {
            int f   = (w * 2 + i) * 64 + lane;
            int row = f >> 2;
            int ko  = (f & 3) << 3;
            gl_lds16(Bt + (size_t)(n0 + row) * K + kt + ko,
                     (char*)B_s + ((w * 2 + i) << 10));
        }
        if (AMODE == 1) {
            const u16* ab = (const u16*)Ap;
#pragma unroll
            for (int i = 0; i < 2; ++i) {
                int f   = (w * 2 + i) * 64 + lane;
                int row = f >> 2;
                int ko  = (f & 3) << 3;
                gl_lds16(ab + (size_t)(m0 + row) * K + kt + ko,
                         (char*)A_s + ((w * 2 + i) << 10));
            }
        } else {
            const float* xa = (const float*)Ap;
#pragma unroll
            for (int i = 0; i < 4; ++i) {
                int c   = t + (i << 8);
                int row = c >> 3;
                int ko  = (c & 7) << 2;
                float4 v = *(const float4*)(xa + (size_t)(m0 + row) * K + kt + ko);
                u16x4 p;
                p[0] = f2bf(v.x); p[1] = f2bf(v.y); p[2] = f2bf(v.z); p[3] = f2bf(v.w);
                *(u16x4*)&A_s[row * 32 + ko] = p;
            }
        }
        __syncthreads();

        bf16x8 af[4], bv[4];
#pragma unroll
        for (int i = 0; i < 4; ++i)
            af[i] = *(const bf16x8*)&A_s[(wy * 64 + i * 16 + lr) * 32 + kq];
#pragma unroll
        for (int j = 0; j < 4; ++j)
            bv[j] = *(const bf16x8*)&B_s[(wx * 64 + j * 16 + lr) * 32 + kq];
#pragma unroll
        for (int i = 0; i < 4; ++i)
#pragma unroll
            for (int j = 0; j < 4; ++j)
                acc[i][j] = __builtin_amdgcn_mfma_f32_16x16x32_bf16(
                    af[i], bv[j], acc[i][j], 0, 0, 0);
        __syncthreads();
    }

    const int r0 = (lane >> 4) << 2, cc = lane & 15;
#pragma unroll
    for (int i = 0; i < 4; ++i)
#pragma unroll
        for (int j = 0; j < 4; ++j)
#pragma unroll
            for (int r = 0; r < 4; ++r) {
                size_t row = (size_t)(m0 + wy * 64 + i * 16 + r0 + r);
                size_t col = (size_t)(n0 + wx * 64 + j * 16 + cc);
                size_t idx = row * (size_t)N + col;
                float v = acc[i][j][r];
                if (EPI == 0) {
                    ghp[idx] = f2bf(v);
                } else if (EPI == 1) {
                    float g  = bf2f(ghp[idx]);
                    float sg = g / (1.0f + __expf(-g));
                    ghp[idx] = f2bf(sg * v);
                } else {
                    outp[idx] = v;
                }
            }
}

extern "C" void kernel_launch(void* const* d_in, const int* in_sizes, int n_in,
                              void* d_out, int out_size, void* d_ws, size_t ws_size,
                              hipStream_t stream) {
    const float* x  = (const float*)d_in[0];
    const int*   gq = (const int*)  d_in[1];
    const float* gs = (const float*)d_in[2];
    const float* gz = (const float*)d_in[3];
    const int*   uq = (const int*)  d_in[4];
    const float* us = (const float*)d_in[5];
    const float* uz = (const float*)d_in[6];
    const int*   dq = (const int*)  d_in[7];
    const float* dsc= (const float*)d_in[8];
    const float* dz = (const float*)d_in[9];
    float* out = (float*)d_out;

    const int D = 4096, I = 11008, M = 8192;
    const size_t xb_b = (size_t)M * D * 2;   //  67.1 MB
    const size_t w_b  = (size_t)I * D * 2;   //  90.2 MB
    const size_t gh_b = (size_t)M * I * 2;   // 180.4 MB

    dim3 blk(256);

    if (ws_size >= xb_b + 2 * w_b + gh_b) {
        // fast path: xb | Wg | Wu | gh ; Wd reuses Wg slot after gu_gemm
        u16* xb = (u16*)d_ws;
        u16* Wg = (u16*)((char*)d_ws + xb_b);
        u16* Wu = (u16*)((char*)d_ws + xb_b + w_b);
        u16* gh = (u16*)((char*)d_ws + xb_b + 2 * w_b);
        u16* Wd = Wg;

        xcvt<<<(M * D) / (256 * 8), blk, 0, stream>>>(x, xb);
        dequant_t<<<dim3(I / 64, D / 128), blk, 0, stream>>>(gq, gs, gz, Wg, D, I);
        dequant_t<<<dim3(I / 64, D / 128), blk, 0, stream>>>(uq, us, uz, Wu, D, I);
        gu_gemm<<<(M / 128) * (I / 128), blk, 0, stream>>>(xb, Wg, Wu, gh, M, I, D);
        dequant_t<<<dim3(D / 64, I / 128), blk, 0, stream>>>(dq, dsc, dz, Wd, I, D);
        gemm_k<1, 2><<<(M / 128) * (D / 128), blk, 0, stream>>>(gh, Wd, nullptr, out, M, D, I);
    } else {
        // fallback: sequential R1 layout (Wt | gh), still gets fast dequant + swizzle
        u16* Wt = (u16*)d_ws;
        u16* gh = (u16*)((char*)d_ws + w_b);

        dequant_t<<<dim3(I / 64, D / 128), blk, 0, stream>>>(gq, gs, gz, Wt, D, I);
        gemm_k<0, 0><<<(M / 128) * (I / 128), blk, 0, stream>>>(x, Wt, gh, nullptr, M, I, D);
        dequant_t<<<dim3(I / 64, D / 128), blk, 0, stream>>>(uq, us, uz, Wt, D, I);
        gemm_k<0, 1><<<(M / 128) * (I / 128), blk, 0, stream>>>(x, Wt, gh, nullptr, M, I, D);
        dequant_t<<<dim3(D / 64, I / 128), blk, 0, stream>>>(dq, dsc, dz, Wt, I, D);
        gemm_k<1, 2><<<(M / 128) * (D / 128), blk, 0, stream>>>(gh, Wt, nullptr, out, M, D, I);
    }
}